// Round 1
// baseline (56.538 us; speedup 1.0000x reference)
//
#include <hip/hip_runtime.h>
#include <math.h>

// Spherical harmonics Y_l^m, l=0..3, per 3-vector. Output [P][16][2] f32.
// One thread per point; all math in registers; 8x float4 stores.

__global__ __launch_bounds__(256) void spharm_kernel(const float* __restrict__ X,
                                                     float* __restrict__ out,
                                                     int npts) {
    int p = blockIdx.x * blockDim.x + threadIdx.x;
    if (p >= npts) return;

    float x = X[(size_t)p * 3 + 0];
    float y = X[(size_t)p * 3 + 1];
    float z = X[(size_t)p * 3 + 2];

    float r2    = x * x + y * y + z * z;
    float inv_r = rsqrtf(r2);
    float ct    = z * inv_r;                       // cos(theta)
    float st    = sqrtf(fmaxf(1.0f - ct * ct, 0.0f)); // sin(theta), matches ref clip

    // cos(phi), sin(phi) without atan2: x/rxy, y/rxy (guard rxy==0 -> phi=0)
    float rxy2    = x * x + y * y;
    float inv_rxy = rsqrtf(rxy2);
    float c1 = x * inv_rxy;
    float s1 = y * inv_rxy;
    if (rxy2 < 1e-35f) { c1 = 1.0f; s1 = 0.0f; }

    // cos/sin of m*phi via angle-addition (Chebyshev) recurrence
    float c2 = c1 * c1 - s1 * s1;
    float s2 = 2.0f * c1 * s1;
    float c3 = c2 * c1 - s2 * s1;
    float s3 = s2 * c1 + c2 * s1;

    // Associated Legendre P_l^m(ct) (Condon-Shortley in P_m^m), closed form
    float ct2 = ct * ct;
    float st2 = st * st;
    float P10 = ct;
    float P11 = -st;
    float P20 = 1.5f * ct2 - 0.5f;
    float P21 = -3.0f * ct * st;
    float P22 = 3.0f * st2;
    float P30 = ct * (2.5f * ct2 - 1.5f);
    float P31 = -1.5f * st * (5.0f * ct2 - 1.0f);
    float P32 = 15.0f * ct * st2;
    float P33 = -15.0f * st * st2;

    // Orthonormal normalization sqrt((2l+1)/(4pi) * (l-m)!/(l+m)!)
    const float N00 = 0.28209479177387814f;
    const float N10 = 0.4886025119029199f;
    const float N11 = 0.3454941494713355f;
    const float N20 = 0.6307831305050401f;
    const float N21 = 0.2575161346821672f;
    const float N22 = 0.12875806734108335f;
    const float N30 = 0.7463526651802308f;
    const float N31 = 0.21545345607610053f;
    const float N32 = 0.06813236509555388f;
    const float N33 = 0.027814921575518937f;

    float b11 = N11 * P11;
    float b21 = N21 * P21;
    float b22 = N22 * P22;
    float b31 = N31 * P31;
    float b32 = N32 * P32;
    float b33 = N33 * P33;

    float b11r = b11 * c1, b11i = b11 * s1;
    float b21r = b21 * c1, b21i = b21 * s1;
    float b22r = b22 * c2, b22i = b22 * s2;
    float b31r = b31 * c1, b31i = b31 * s1;
    float b32r = b32 * c2, b32i = b32 * s2;
    float b33r = b33 * c3, b33i = b33 * s3;

    // Layout per point: k = l^2 + (l + m), each (re, im).
    // m<0: re = sgn*base*cos, im = -sgn*base*sin, sgn = (-1)^|m|
    float4* ov = (float4*)(out + (size_t)p * 32);
    ov[0] = make_float4(N00,       0.0f,  -b11r,  b11i);   // Y00 | Y1,-1
    ov[1] = make_float4(N10 * P10, 0.0f,   b11r,  b11i);   // Y10 | Y11
    ov[2] = make_float4(b22r,     -b22i,  -b21r,  b21i);   // Y2,-2 | Y2,-1
    ov[3] = make_float4(N20 * P20, 0.0f,   b21r,  b21i);   // Y20 | Y21
    ov[4] = make_float4(b22r,      b22i,  -b33r,  b33i);   // Y22 | Y3,-3
    ov[5] = make_float4(b32r,     -b32i,  -b31r,  b31i);   // Y3,-2 | Y3,-1
    ov[6] = make_float4(N30 * P30, 0.0f,   b31r,  b31i);   // Y30 | Y31
    ov[7] = make_float4(b32r,      b32i,   b33r,  b33i);   // Y32 | Y33
}

extern "C" void kernel_launch(void* const* d_in, const int* in_sizes, int n_in,
                              void* d_out, int out_size, void* d_ws, size_t ws_size,
                              hipStream_t stream) {
    const float* X = (const float*)d_in[0];
    float* out = (float*)d_out;
    int npts = in_sizes[0] / 3;        // 4*512*512
    int block = 256;
    int grid = (npts + block - 1) / block;
    spharm_kernel<<<grid, block, 0, stream>>>(X, out, npts);
}

// Round 2
// 27.730 us; speedup vs baseline: 2.0389x; 2.0389x over previous
//
#include <hip/hip_runtime.h>
#include <math.h>

// Spherical harmonics Y_l^m, l=0..3, per 3-vector. Output [P][16][2] f32.
// One thread per point; math in registers; output staged in LDS (XOR-swizzled)
// then written back as fully-coalesced float4 bursts (1 KB/wave/instr).

__global__ __launch_bounds__(256) void spharm_kernel(const float* __restrict__ X,
                                                     float* __restrict__ out,
                                                     int npts) {
    __shared__ float lds[256 * 32];          // 32 KB: 256 points x 32 floats
    const int t = threadIdx.x;
    const int p = blockIdx.x * 256 + t;      // npts divisible by 256 (4*512*512)

    float x = X[(size_t)p * 3 + 0];
    float y = X[(size_t)p * 3 + 1];
    float z = X[(size_t)p * 3 + 2];

    float r2    = x * x + y * y + z * z;
    float inv_r = rsqrtf(r2);
    float ct    = z * inv_r;                          // cos(theta)
    float st    = sqrtf(fmaxf(1.0f - ct * ct, 0.0f)); // sin(theta), matches ref clip

    // cos(phi), sin(phi) without atan2 (guard rxy==0 -> phi=0)
    float rxy2    = x * x + y * y;
    float inv_rxy = rsqrtf(rxy2);
    float c1 = x * inv_rxy;
    float s1 = y * inv_rxy;
    if (rxy2 < 1e-35f) { c1 = 1.0f; s1 = 0.0f; }

    // cos/sin of m*phi via angle-addition recurrence
    float c2 = c1 * c1 - s1 * s1;
    float s2 = 2.0f * c1 * s1;
    float c3 = c2 * c1 - s2 * s1;
    float s3 = s2 * c1 + c2 * s1;

    // Associated Legendre P_l^m(ct) (Condon-Shortley), closed form for l<=3
    float ct2 = ct * ct;
    float st2 = st * st;
    float P10 = ct;
    float P11 = -st;
    float P20 = 1.5f * ct2 - 0.5f;
    float P21 = -3.0f * ct * st;
    float P22 = 3.0f * st2;
    float P30 = ct * (2.5f * ct2 - 1.5f);
    float P31 = -1.5f * st * (5.0f * ct2 - 1.0f);
    float P32 = 15.0f * ct * st2;
    float P33 = -15.0f * st * st2;

    // Orthonormal normalization sqrt((2l+1)/(4pi) * (l-m)!/(l+m)!)
    const float N00 = 0.28209479177387814f;
    const float N10 = 0.4886025119029199f;
    const float N11 = 0.3454941494713355f;
    const float N20 = 0.6307831305050401f;
    const float N21 = 0.2575161346821672f;
    const float N22 = 0.12875806734108335f;
    const float N30 = 0.7463526651802308f;
    const float N31 = 0.21545345607610053f;
    const float N32 = 0.06813236509555388f;
    const float N33 = 0.027814921575518937f;

    float b11 = N11 * P11;
    float b21 = N21 * P21;
    float b22 = N22 * P22;
    float b31 = N31 * P31;
    float b32 = N32 * P32;
    float b33 = N33 * P33;

    float b11r = b11 * c1, b11i = b11 * s1;
    float b21r = b21 * c1, b21i = b21 * s1;
    float b22r = b22 * c2, b22i = b22 * s2;
    float b31r = b31 * c1, b31i = b31 * s1;
    float b32r = b32 * c2, b32i = b32 * s2;
    float b33r = b33 * c3, b33i = b33 * s3;

    // Per-point layout: k = l^2 + (l + m), each (re, im).
    // m<0: re = sgn*base*cos, im = -sgn*base*sin, sgn = (-1)^|m|
    float4 f[8];
    f[0] = make_float4(N00,       0.0f,  -b11r,  b11i);   // Y00 | Y1,-1
    f[1] = make_float4(N10 * P10, 0.0f,   b11r,  b11i);   // Y10 | Y11
    f[2] = make_float4(b22r,     -b22i,  -b21r,  b21i);   // Y2,-2 | Y2,-1
    f[3] = make_float4(N20 * P20, 0.0f,   b21r,  b21i);   // Y20 | Y21
    f[4] = make_float4(b22r,      b22i,  -b33r,  b33i);   // Y22 | Y3,-3
    f[5] = make_float4(b32r,     -b32i,  -b31r,  b31i);   // Y3,-2 | Y3,-1
    f[6] = make_float4(N30 * P30, 0.0f,   b31r,  b31i);   // Y30 | Y31
    f[7] = make_float4(b32r,      b32i,   b33r,  b33i);   // Y32 | Y33

    // Stage to LDS. float4 slot for (point pp, quad jq) = pp*8 + (jq ^ (pp&7)).
    // XOR swizzle spreads the 8 lanes/bank-group bandwidth floor evenly for
    // both the write (per-point) and the read (per-output-offset) patterns.
    float4* lv = (float4*)lds;
#pragma unroll
    for (int jq = 0; jq < 8; ++jq) {
        lv[t * 8 + (jq ^ (t & 7))] = f[jq];
    }

    __syncthreads();

    // Coalesced writeback: iteration i stores block-local float4s [i*256 + t].
    float4* og = (float4*)out + (size_t)blockIdx.x * 2048;
#pragma unroll
    for (int i = 0; i < 8; ++i) {
        int pp = i * 32 + (t >> 3);                       // point owning this quad
        float4 v = lv[pp * 8 + ((t & 7) ^ (pp & 7))];
        og[i * 256 + t] = v;
    }
}

extern "C" void kernel_launch(void* const* d_in, const int* in_sizes, int n_in,
                              void* d_out, int out_size, void* d_ws, size_t ws_size,
                              hipStream_t stream) {
    const float* X = (const float*)d_in[0];
    float* out = (float*)d_out;
    int npts = in_sizes[0] / 3;        // 4*512*512 = 1048576, divisible by 256
    int block = 256;
    int grid = npts / block;
    spharm_kernel<<<grid, block, 0, stream>>>(X, out, npts);
}